// Round 18
// baseline (103.788 us; speedup 1.0000x reference)
//
#include <hip/hip_runtime.h>

#define HW 2304
#define WID 48

typedef __attribute__((ext_vector_type(8))) short bf16x8;
typedef __attribute__((ext_vector_type(4))) float f32x4;
typedef __attribute__((ext_vector_type(2))) _Float16 half2v;

__device__ __forceinline__ half2v pk_h2(float lo, float hi) {
  return __builtin_bit_cast(half2v, __builtin_amdgcn_cvt_pkrtz(lo, hi));
}

__device__ __forceinline__ unsigned pack_bf2(float lo, float hi) {
  unsigned a = __builtin_bit_cast(unsigned, lo);
  unsigned b = __builtin_bit_cast(unsigned, hi);
  a = (a + 0x7FFFu + ((a >> 16) & 1u)) >> 16;
  b = (b + 0x7FFFu + ((b >> 16) & 1u)) >> 16;
  return a | (b << 16);
}
__device__ __forceinline__ unsigned short bf16_of(float x) {
  unsigned u = __builtin_bit_cast(unsigned, x);
  u = (u + 0x7FFFu + ((u >> 16) & 1u)) >> 16;
  return (unsigned short)u;
}
__device__ __forceinline__ unsigned short f16_of(float x) {
  _Float16 h = (_Float16)x;
  return __builtin_bit_cast(unsigned short, h);
}

// ---------------- Weight prep: fp32 [N][K] -> fragment-ordered bf16
__global__ __launch_bounds__(256) void prep_w(
    const float* __restrict__ wq, const float* __restrict__ wk,
    const float* __restrict__ wv, const float* __restrict__ w1,
    const float* __restrict__ w2, unsigned* __restrict__ wf)
{
  int fid = blockIdx.x * 4 + (threadIdx.x >> 6);
  int l = threadIdx.x & 63;
  const float* src; int K; int base;
  if (fid < 72)       { src = wq; K = 192; base = 0; }
  else if (fid < 144) { src = wk; K = 192; base = 72; }
  else if (fid < 216) { src = wv; K = 192; base = 144; }
  else if (fid < 360) { src = w1; K = 192; base = 216; }
  else                { src = w2; K = 384; base = 360; }
  int local = fid - base;
  int KS = K / 32;
  int nf = local / KS, ks = local % KS;
  int row = nf * 16 + (l & 15);
  int c0 = ks * 32 + (l >> 4) * 8;
  const float* p = src + (size_t)row * K + c0;
  float4 v0 = *(const float4*)p;
  float4 v1 = *(const float4*)(p + 4);
  unsigned* dst = wf + ((size_t)fid * 64 + l) * 4;
  dst[0] = pack_bf2(v0.x, v0.y);
  dst[1] = pack_bf2(v0.z, v0.w);
  dst[2] = pack_bf2(v1.x, v1.y);
  dst[3] = pack_bf2(v1.z, v1.w);
}

// ---------------- Projection via MFMA. q slab -> fp32 qp [B][HW][192];
// k/v slabs -> f16 kvp [bc][kv][pk(6)][HW][32ch] (64B per pixel-headpair entry)
__global__ __launch_bounds__(256) void proj_mfma(
    const float* __restrict__ q, const float* __restrict__ k, const float* __restrict__ v,
    const unsigned* __restrict__ wf,
    const float* __restrict__ bq, const float* __restrict__ bk, const float* __restrict__ bv,
    float* __restrict__ qp, unsigned short* __restrict__ kvp)
{
  __shared__ unsigned lds[64 * 100];
  int slab = blockIdx.y;
  const float* in; const unsigned* wfr; const float* bias;
  float* outf = nullptr; unsigned short* outh = nullptr;
  if (slab < 4) {
    in = q + (size_t)slab * 192 * HW; wfr = wf; bias = bq;
    outf = qp + (size_t)slab * HW * 192;
  } else if (slab < 12) {
    int c = slab - 4;
    in = k + (size_t)c * 192 * HW; wfr = wf + 72 * 256; bias = bk;
    outh = kvp + (size_t)c * 2 * 6 * HW * 32;            // kv=0
  } else {
    int c = slab - 12;
    in = v + (size_t)c * 192 * HW; wfr = wf + 144 * 256; bias = bv;
    outh = kvp + ((size_t)c * 2 + 1) * 6 * HW * 32;      // kv=1
  }
  const int n0 = blockIdx.x * 64;
  const int t = threadIdx.x;
  const int w = t >> 6, l = t & 63;

  {
    int pix = t & 63;
    int cp0 = t >> 6;
    const float* s0 = in + n0 + pix;
#pragma unroll
    for (int i = 0; i < 24; ++i) {
      int cp = cp0 * 24 + i;
      float lo = s0[(size_t)(2 * cp) * HW];
      float hi = s0[(size_t)(2 * cp + 1) * HW];
      lds[pix * 100 + cp] = pack_bf2(lo, hi);
    }
  }

  bf16x8 wfrag[6][3];
#pragma unroll
  for (int ks = 0; ks < 6; ++ks)
#pragma unroll
    for (int nfi = 0; nfi < 3; ++nfi) {
      int nf = w * 3 + nfi;
      wfrag[ks][nfi] = ((const bf16x8*)wfr)[(nf * 6 + ks) * 64 + l];
    }

  __syncthreads();

  f32x4 acc[3][4];
#pragma unroll
  for (int a = 0; a < 3; ++a)
#pragma unroll
    for (int m = 0; m < 4; ++m) acc[a][m] = (f32x4){0.f, 0.f, 0.f, 0.f};

#pragma unroll
  for (int ks = 0; ks < 6; ++ks) {
    bf16x8 af[4];
#pragma unroll
    for (int mf = 0; mf < 4; ++mf)
      af[mf] = *(const bf16x8*)&lds[(mf * 16 + (l & 15)) * 100 + ks * 16 + (l >> 4) * 4];
#pragma unroll
    for (int nfi = 0; nfi < 3; ++nfi)
#pragma unroll
      for (int mf = 0; mf < 4; ++mf)
        acc[nfi][mf] = __builtin_amdgcn_mfma_f32_16x16x32_bf16(af[mf], wfrag[ks][nfi], acc[nfi][mf], 0, 0, 0);
  }

#pragma unroll
  for (int nfi = 0; nfi < 3; ++nfi) {
    int oc = (w * 3 + nfi) * 16 + (l & 15);
    float bs = bias[oc];
    if (outf) {
#pragma unroll
      for (int mf = 0; mf < 4; ++mf) {
        int pixb = n0 + mf * 16 + (l >> 4) * 4;
#pragma unroll
        for (int j = 0; j < 4; ++j)
          outf[(size_t)(pixb + j) * 192 + oc] = acc[nfi][mf][j] + bs;
      }
    } else {
      int pkh = oc >> 5, ch = oc & 31;
#pragma unroll
      for (int mf = 0; mf < 4; ++mf) {
        int pixb = n0 + mf * 16 + (l >> 4) * 4;
#pragma unroll
        for (int j = 0; j < 4; ++j)
          outh[((size_t)pkh * HW + pixb + j) * 32 + ch] = f16_of(acc[nfi][mf][j] + bs);
      }
    }
  }
}

// ---------------- Deformable attention with LDS-windowed gathers.
// block = (b, half, head-pair, 32-pixel tile); 8 lanes/pixel = 2 corner-slots
// x 4 channel-quarters. Per clip, stage a 13-row plane window (39KB) into LDS;
// gather via DS (5x faster address processing than TA); rare out-of-window
// samples (|oy| outside [-3,4)) fall back to predicated global loads.
__global__ __launch_bounds__(256, 2) void attn_kernel(
    const float* __restrict__ qp, const unsigned short* __restrict__ kvp,
    const float* __restrict__ offs, float* __restrict__ o_ws)
{
  __shared__ uint4 rec[2][2][9][32];        // 18432 B
  __shared__ unsigned short win[624 * 32];  // 39936 B window buffer
  const int t = threadIdx.x;
  const int g = blockIdx.x & 7;          // (b, half) -> XCD-resident KV slab
  const int pos = blockIdx.x >> 3;       // 0..215
  const int b = g >> 1;
  const int half = g & 1;
  const int pk = pos / 36;
  const int tile = pos % 36;
  const int n_base = half * 1152 + tile * 32;

  const int hh_lo = n_base / WID;
  const int hh_hi = (n_base + 31) / WID;
  int wlo = hh_lo - 5; if (wlo < 0) wlo = 0;
  int whi = hh_hi + 6; if (whi > 47) whi = 47;
  const unsigned wlo48 = (unsigned)(wlo * WID);
  const unsigned wlen = (unsigned)((whi - wlo + 1) * WID);   // <= 624

  // ---- in-block record computation: 1152 records, ~4.5 per thread
#pragma unroll
  for (int i = 0; i < 5; ++i) {
    int rid = t + i * 256;
    if (rid < 1152) {
      int rpix = rid & 31;
      int rest = rid >> 5;               // 0..35 = (dgsel, clip, tap)
      int rtap = rest % 9;
      int rq = rest / 9;                 // 0..3
      int rclip = rq & 1;
      int dgsel = rq >> 1;
      int rn = n_base + rpix;
      int rh = rn / WID, rw = rn % WID;
      int dg = pk + dgsel * 6;
      const float* ob = offs + ((size_t)(b * 2 + rclip) * 216 + (size_t)(dg * 9 + rtap) * 2) * HW + rn;
      float oy = ob[0];
      float ox = ob[HW];
      float py = (float)(rh - 1 + rtap / 3) + oy;
      float px = (float)(rw - 1 + rtap % 3) + ox;
      float y0f = floorf(py), x0f = floorf(px);
      int y0 = (int)y0f, x0 = (int)x0f;
      float wy1 = py - y0f, wx1 = px - x0f;
      float wy0 = 1.f - wy1, wx0 = 1.f - wx1;
      unsigned ip[2];
      float wv[4];
#pragma unroll
      for (int cy = 0; cy < 2; ++cy) {
        int yi = y0 + cy;
        float wyv = cy ? wy1 : wy0;
        int yc = yi < 0 ? 0 : (yi > 47 ? 47 : yi);
        bool vy = (unsigned)yi < 48u;
#pragma unroll
        for (int cx = 0; cx < 2; ++cx) {
          int xi = x0 + cx;
          float wxv = cx ? wx1 : wx0;
          int xc = xi < 0 ? 0 : (xi > 47 ? 47 : xi);
          bool vx = (unsigned)xi < 48u;
          float wgt = (vy && vx) ? wyv * wxv : 0.f;
          int ci = cy * 2 + cx;
          wv[ci] = wgt;
          ((unsigned short*)ip)[ci] = (unsigned short)(yc * WID + xc);
        }
      }
      uint4 rc;
      rc.x = ip[0];
      rc.y = ip[1];
      rc.z = __builtin_bit_cast(unsigned, pk_h2(wv[0], wv[1]));
      rc.w = __builtin_bit_cast(unsigned, pk_h2(wv[2], wv[3]));
      rec[dgsel][rclip][rtap][rpix] = rc;
    }
  }

  const int l8 = t & 7;
  const int csel = l8 >> 2;      // corner slot: 0 -> A/C, 1 -> B/D
  const int chq = l8 & 3;        // 8-channel quarter within the 32-ch head-pair
  const int pix = t >> 3;
  const int n = n_base + pix;

  // q: 8 channels for this lane's quarter
  half2v qh[4];
  {
    const float* qb = qp + ((size_t)b * HW + n) * 192 + pk * 32 + chq * 8;
    float4 v0 = *(const float4*)qb;
    float4 v1 = *(const float4*)(qb + 4);
    qh[0] = pk_h2(v0.x * 0.25f, v0.y * 0.25f);
    qh[1] = pk_h2(v0.z * 0.25f, v0.w * 0.25f);
    qh[2] = pk_h2(v1.x * 0.25f, v1.y * 0.25f);
    qh[3] = pk_h2(v1.z * 0.25f, v1.w * 0.25f);
  }

  float sc[18];

  // ---- K phase: per clip, stage window then gather from LDS
  for (int c = 0; c < 2; ++c) {
    const unsigned short* kplane = kvp + (((size_t)(b * 2 + c) * 2 + 0) * 6 + pk) * HW * 32;
    {
      const uint4* src4 = (const uint4*)(kplane + (size_t)wlo48 * 32);
      uint4* dst4 = (uint4*)win;
      for (int i = t; i < (int)(wlen * 4); i += 256) dst4[i] = src4[i];
    }
    __syncthreads();
    const unsigned short* kb = kplane + chq * 8;
#pragma unroll
    for (int kk = 0; kk < 9; ++kk) {
      uint4 rc = rec[0][c][kk][pix];
      float s = 0.f;
#pragma unroll
      for (int r = 0; r < 2; ++r) {
        unsigned pr = r ? rc.y : rc.x;
        unsigned idx = csel ? (pr >> 16) : (pr & 0xFFFFu);
        half2v wp = __builtin_bit_cast(half2v, r ? rc.w : rc.z);
        _Float16 wh = csel ? wp.y : wp.x;
        unsigned rel = idx - wlo48;
        uint4 u;
        if (rel < wlen) u = *(const uint4*)(win + rel * 32 + chq * 8);
        else            u = *(const uint4*)(kb + (size_t)idx * 32);
        float d = __builtin_amdgcn_fdot2(qh[0], __builtin_bit_cast(half2v, u.x), 0.f, false);
        d = __builtin_amdgcn_fdot2(qh[1], __builtin_bit_cast(half2v, u.y), d, false);
        d = __builtin_amdgcn_fdot2(qh[2], __builtin_bit_cast(half2v, u.z), d, false);
        d = __builtin_amdgcn_fdot2(qh[3], __builtin_bit_cast(half2v, u.w), d, false);
        s += (float)wh * d;
      }
      sc[c * 9 + kk] = s;
    }
    __syncthreads();
  }

  // ---- batched cross-lane reduction
#pragma unroll
  for (int j = 0; j < 18; ++j) sc[j] += __shfl_xor(sc[j], 1, 64);
#pragma unroll
  for (int j = 0; j < 18; ++j) sc[j] += __shfl_xor(sc[j], 4, 64);

  // ---- softmax over 18 taps (in registers, redundant per lane)
  {
    float m = -1e30f;
#pragma unroll
    for (int j = 0; j < 18; ++j) m = fmaxf(m, sc[j]);
    float sum = 0.f;
#pragma unroll
    for (int j = 0; j < 18; ++j) { float ev = __expf(sc[j] - m); sc[j] = ev; sum += ev; }
    float inv = 1.f / sum;
#pragma unroll
    for (int j = 0; j < 18; ++j) sc[j] *= inv;
  }

  // ---- V phase: per clip, stage window then gather from LDS
  float acc[8];
#pragma unroll
  for (int i = 0; i < 8; ++i) acc[i] = 0.f;
  for (int c = 0; c < 2; ++c) {
    const unsigned short* vplane = kvp + (((size_t)(b * 2 + c) * 2 + 1) * 6 + pk) * HW * 32;
    {
      const uint4* src4 = (const uint4*)(vplane + (size_t)wlo48 * 32);
      uint4* dst4 = (uint4*)win;
      for (int i = t; i < (int)(wlen * 4); i += 256) dst4[i] = src4[i];
    }
    __syncthreads();
    const unsigned short* vb = vplane + chq * 8;
#pragma unroll
    for (int kk = 0; kk < 9; ++kk) {
      uint4 rc = rec[1][c][kk][pix];
      float at = sc[c * 9 + kk];
#pragma unroll
      for (int r = 0; r < 2; ++r) {
        unsigned pr = r ? rc.y : rc.x;
        unsigned idx = csel ? (pr >> 16) : (pr & 0xFFFFu);
        half2v wp = __builtin_bit_cast(half2v, r ? rc.w : rc.z);
        _Float16 wh = csel ? wp.y : wp.x;
        unsigned rel = idx - wlo48;
        uint4 u;
        if (rel < wlen) u = *(const uint4*)(win + rel * 32 + chq * 8);
        else            u = *(const uint4*)(vb + (size_t)idx * 32);
        float cw = (float)wh * at;
        half2v v0 = __builtin_bit_cast(half2v, u.x);
        half2v v1 = __builtin_bit_cast(half2v, u.y);
        half2v v2 = __builtin_bit_cast(half2v, u.z);
        half2v v3 = __builtin_bit_cast(half2v, u.w);
        acc[0] += cw * (float)v0.x; acc[1] += cw * (float)v0.y;
        acc[2] += cw * (float)v1.x; acc[3] += cw * (float)v1.y;
        acc[4] += cw * (float)v2.x; acc[5] += cw * (float)v2.y;
        acc[6] += cw * (float)v3.x; acc[7] += cw * (float)v3.y;
      }
    }
    __syncthreads();
  }

  // cross-corner-lane reduce (lane ^ 4 holds the other corner slot)
#pragma unroll
  for (int i = 0; i < 8; ++i) acc[i] += __shfl_xor(acc[i], 4, 64);

  if (csel == 0) {
    float* orow = o_ws + ((size_t)b * HW + n) * 192 + pk * 32 + chq * 8;
    float4 r0; r0.x = acc[0]; r0.y = acc[1]; r0.z = acc[2]; r0.w = acc[3];
    float4 r1; r1.x = acc[4]; r1.y = acc[5]; r1.z = acc[6]; r1.w = acc[7];
    *(float4*)orow = r0;
    *(float4*)(orow + 4) = r1;
  }
}

// ---------------- MLP via MFMA: one block per 16-pixel tile
__global__ __launch_bounds__(256) void mlp_mfma(
    const float* __restrict__ o_ws, const unsigned* __restrict__ wf,
    const float* __restrict__ b1, const float* __restrict__ b2,
    float* __restrict__ out)
{
  __shared__ unsigned ldsO[16 * 100];
  __shared__ unsigned ldsH[16 * 196];
  const unsigned* w1f = wf + 216 * 256;
  const unsigned* w2f = wf + 360 * 256;
  const int blk = blockIdx.x;
  const int b = blk / 144;
  const int n0 = (blk % 144) * 16;
  const int t = threadIdx.x;
  const int w = t >> 6, l = t & 63;

  for (int i = t; i < 16 * 96; i += 256) {
    int pix = i / 96, cp = i % 96;
    const float2 s = *(const float2*)(o_ws + ((size_t)(b * HW) + n0 + pix) * 192 + 2 * cp);
    ldsO[pix * 100 + cp] = pack_bf2(s.x, s.y);
  }
  __syncthreads();

  f32x4 acc1[6];
#pragma unroll
  for (int a = 0; a < 6; ++a) acc1[a] = (f32x4){0.f, 0.f, 0.f, 0.f};
#pragma unroll
  for (int ks = 0; ks < 6; ++ks) {
    bf16x8 af = *(const bf16x8*)&ldsO[(l & 15) * 100 + ks * 16 + (l >> 4) * 4];
#pragma unroll
    for (int nfi = 0; nfi < 6; ++nfi) {
      int nf = w * 6 + nfi;
      bf16x8 bfr = ((const bf16x8*)w1f)[(nf * 6 + ks) * 64 + l];
      acc1[nfi] = __builtin_amdgcn_mfma_f32_16x16x32_bf16(af, bfr, acc1[nfi], 0, 0, 0);
    }
  }

  {
    unsigned short* ldsHu = (unsigned short*)ldsH;
#pragma unroll
    for (int nfi = 0; nfi < 6; ++nfi) {
      int hc = (w * 6 + nfi) * 16 + (l & 15);
      float bs = b1[hc];
#pragma unroll
      for (int j = 0; j < 4; ++j) {
        int pix = (l >> 4) * 4 + j;
        float x = acc1[nfi][j] + bs;
        float gl = 0.5f * x * (1.f + erff(x * 0.70710678118654752f));
        ldsHu[pix * 392 + hc] = bf16_of(gl);
      }
    }
  }
  __syncthreads();

  f32x4 acc2[3];
#pragma unroll
  for (int a = 0; a < 3; ++a) acc2[a] = (f32x4){0.f, 0.f, 0.f, 0.f};
#pragma unroll
  for (int ks = 0; ks < 12; ++ks) {
    bf16x8 af = *(const bf16x8*)&ldsH[(l & 15) * 196 + ks * 16 + (l >> 4) * 4];
#pragma unroll
    for (int nfi = 0; nfi < 3; ++nfi) {
      int nf = w * 3 + nfi;
      bf16x8 bfr = ((const bf16x8*)w2f)[(nf * 12 + ks) * 64 + l];
      acc2[nfi] = __builtin_amdgcn_mfma_f32_16x16x32_bf16(af, bfr, acc2[nfi], 0, 0, 0);
    }
  }

#pragma unroll
  for (int nfi = 0; nfi < 3; ++nfi) {
    int oc = (w * 3 + nfi) * 16 + (l & 15);
    float bs = b2[oc];
#pragma unroll
    for (int j = 0; j < 4; ++j) {
      int pix = (l >> 4) * 4 + j;
      float res = o_ws[((size_t)(b * HW) + n0 + pix) * 192 + oc];
      out[((size_t)b * 192 + oc) * HW + n0 + pix] = acc2[nfi][j] + bs + res;
    }
  }
}

extern "C" void kernel_launch(void* const* d_in, const int* in_sizes, int n_in,
                              void* d_out, int out_size, void* d_ws, size_t ws_size,
                              hipStream_t stream) {
  const float* q = (const float*)d_in[0];
  const float* k = (const float*)d_in[1];
  const float* v = (const float*)d_in[2];
  const float* offset = (const float*)d_in[3];
  const float* wq = (const float*)d_in[4];
  const float* bq = (const float*)d_in[5];
  const float* wk = (const float*)d_in[6];
  const float* bk = (const float*)d_in[7];
  const float* wv = (const float*)d_in[8];
  const float* bv = (const float*)d_in[9];
  const float* w1 = (const float*)d_in[10];
  const float* b1 = (const float*)d_in[11];
  const float* w2 = (const float*)d_in[12];
  const float* b2 = (const float*)d_in[13];
  float* out = (float*)d_out;

  float* qp_t = (float*)d_ws;                                    // 4*2304*192 f32
  float* o_ws = qp_t + (size_t)4 * HW * 192;                     // 4*2304*192 f32
  unsigned short* kvp = (unsigned short*)(o_ws + (size_t)4 * HW * 192);  // 8*2*6*2304*32 u16
  unsigned* wfb = (unsigned*)(kvp + (size_t)8 * 2 * 6 * HW * 32);        // 504*256 u32

  prep_w<<<dim3(126), dim3(256), 0, stream>>>(wq, wk, wv, w1, w2, wfb);
  proj_mfma<<<dim3(36, 20), dim3(256), 0, stream>>>(q, k, v, wfb, bq, bk, bv, qp_t, kvp);
  attn_kernel<<<dim3(1728), dim3(256), 0, stream>>>(qp_t, kvp, offset, o_ws);
  mlp_mfma<<<dim3(576), dim3(256), 0, stream>>>(o_ws, wfb, b1, b2, out);
}

// Round 19
// 63.717 us; speedup vs baseline: 1.6289x; 1.6289x over previous
//
#include <hip/hip_runtime.h>

#define HW 2304
#define WID 48

typedef __attribute__((ext_vector_type(8))) short bf16x8;
typedef __attribute__((ext_vector_type(4))) float f32x4;
typedef __attribute__((ext_vector_type(2))) _Float16 half2v;

__device__ __forceinline__ half2v pk_h2(float lo, float hi) {
  return __builtin_bit_cast(half2v, __builtin_amdgcn_cvt_pkrtz(lo, hi));
}

__device__ __forceinline__ unsigned pack_bf2(float lo, float hi) {
  unsigned a = __builtin_bit_cast(unsigned, lo);
  unsigned b = __builtin_bit_cast(unsigned, hi);
  a = (a + 0x7FFFu + ((a >> 16) & 1u)) >> 16;
  b = (b + 0x7FFFu + ((b >> 16) & 1u)) >> 16;
  return a | (b << 16);
}
__device__ __forceinline__ unsigned short bf16_of(float x) {
  unsigned u = __builtin_bit_cast(unsigned, x);
  u = (u + 0x7FFFu + ((u >> 16) & 1u)) >> 16;
  return (unsigned short)u;
}
__device__ __forceinline__ unsigned short f16_of(float x) {
  _Float16 h = (_Float16)x;
  return __builtin_bit_cast(unsigned short, h);
}

// ---------------- Weight prep: fp32 [N][K] -> fragment-ordered bf16
__global__ __launch_bounds__(256) void prep_w(
    const float* __restrict__ wq, const float* __restrict__ wk,
    const float* __restrict__ wv, const float* __restrict__ w1,
    const float* __restrict__ w2, unsigned* __restrict__ wf)
{
  int fid = blockIdx.x * 4 + (threadIdx.x >> 6);
  int l = threadIdx.x & 63;
  const float* src; int K; int base;
  if (fid < 72)       { src = wq; K = 192; base = 0; }
  else if (fid < 144) { src = wk; K = 192; base = 72; }
  else if (fid < 216) { src = wv; K = 192; base = 144; }
  else if (fid < 360) { src = w1; K = 192; base = 216; }
  else                { src = w2; K = 384; base = 360; }
  int local = fid - base;
  int KS = K / 32;
  int nf = local / KS, ks = local % KS;
  int row = nf * 16 + (l & 15);
  int c0 = ks * 32 + (l >> 4) * 8;
  const float* p = src + (size_t)row * K + c0;
  float4 v0 = *(const float4*)p;
  float4 v1 = *(const float4*)(p + 4);
  unsigned* dst = wf + ((size_t)fid * 64 + l) * 4;
  dst[0] = pack_bf2(v0.x, v0.y);
  dst[1] = pack_bf2(v0.z, v0.w);
  dst[2] = pack_bf2(v1.x, v1.y);
  dst[3] = pack_bf2(v1.z, v1.w);
}

// ---------------- Projection via MFMA. q slab -> fp32 qp [B][HW][192];
// k/v slabs -> f16 kvp [bc][kv][pk(6)][HW][32ch] (64B per pixel-headpair entry)
__global__ __launch_bounds__(256) void proj_mfma(
    const float* __restrict__ q, const float* __restrict__ k, const float* __restrict__ v,
    const unsigned* __restrict__ wf,
    const float* __restrict__ bq, const float* __restrict__ bk, const float* __restrict__ bv,
    float* __restrict__ qp, unsigned short* __restrict__ kvp)
{
  __shared__ unsigned lds[64 * 100];
  int slab = blockIdx.y;
  const float* in; const unsigned* wfr; const float* bias;
  float* outf = nullptr; unsigned short* outh = nullptr;
  if (slab < 4) {
    in = q + (size_t)slab * 192 * HW; wfr = wf; bias = bq;
    outf = qp + (size_t)slab * HW * 192;
  } else if (slab < 12) {
    int c = slab - 4;
    in = k + (size_t)c * 192 * HW; wfr = wf + 72 * 256; bias = bk;
    outh = kvp + (size_t)c * 2 * 6 * HW * 32;            // kv=0
  } else {
    int c = slab - 12;
    in = v + (size_t)c * 192 * HW; wfr = wf + 144 * 256; bias = bv;
    outh = kvp + ((size_t)c * 2 + 1) * 6 * HW * 32;      // kv=1
  }
  const int n0 = blockIdx.x * 64;
  const int t = threadIdx.x;
  const int w = t >> 6, l = t & 63;

  {
    int pix = t & 63;
    int cp0 = t >> 6;
    const float* s0 = in + n0 + pix;
#pragma unroll
    for (int i = 0; i < 24; ++i) {
      int cp = cp0 * 24 + i;
      float lo = s0[(size_t)(2 * cp) * HW];
      float hi = s0[(size_t)(2 * cp + 1) * HW];
      lds[pix * 100 + cp] = pack_bf2(lo, hi);
    }
  }

  bf16x8 wfrag[6][3];
#pragma unroll
  for (int ks = 0; ks < 6; ++ks)
#pragma unroll
    for (int nfi = 0; nfi < 3; ++nfi) {
      int nf = w * 3 + nfi;
      wfrag[ks][nfi] = ((const bf16x8*)wfr)[(nf * 6 + ks) * 64 + l];
    }

  __syncthreads();

  f32x4 acc[3][4];
#pragma unroll
  for (int a = 0; a < 3; ++a)
#pragma unroll
    for (int m = 0; m < 4; ++m) acc[a][m] = (f32x4){0.f, 0.f, 0.f, 0.f};

#pragma unroll
  for (int ks = 0; ks < 6; ++ks) {
    bf16x8 af[4];
#pragma unroll
    for (int mf = 0; mf < 4; ++mf)
      af[mf] = *(const bf16x8*)&lds[(mf * 16 + (l & 15)) * 100 + ks * 16 + (l >> 4) * 4];
#pragma unroll
    for (int nfi = 0; nfi < 3; ++nfi)
#pragma unroll
      for (int mf = 0; mf < 4; ++mf)
        acc[nfi][mf] = __builtin_amdgcn_mfma_f32_16x16x32_bf16(af[mf], wfrag[ks][nfi], acc[nfi][mf], 0, 0, 0);
  }

#pragma unroll
  for (int nfi = 0; nfi < 3; ++nfi) {
    int oc = (w * 3 + nfi) * 16 + (l & 15);
    float bs = bias[oc];
    if (outf) {
#pragma unroll
      for (int mf = 0; mf < 4; ++mf) {
        int pixb = n0 + mf * 16 + (l >> 4) * 4;
#pragma unroll
        for (int j = 0; j < 4; ++j)
          outf[(size_t)(pixb + j) * 192 + oc] = acc[nfi][mf][j] + bs;
      }
    } else {
      int pkh = oc >> 5, ch = oc & 31;
#pragma unroll
      for (int mf = 0; mf < 4; ++mf) {
        int pixb = n0 + mf * 16 + (l >> 4) * 4;
#pragma unroll
        for (int j = 0; j < 4; ++j)
          outh[((size_t)pkh * HW + pixb + j) * 32 + ch] = f16_of(acc[nfi][mf][j] + bs);
      }
    }
  }
}

// ---------------- Deformable attention (best: round-15): block = (b, half,
// head-pair, 32-pixel tile). 8 lanes per pixel = 2 corner-slots x 4 ch-quarters.
// kvp plane layout -> ~24KB L1-resident window. Records in-block in LDS.
__global__ __launch_bounds__(256, 4) void attn_kernel(
    const float* __restrict__ qp, const unsigned short* __restrict__ kvp,
    const float* __restrict__ offs, float* __restrict__ o_ws)
{
  __shared__ uint4 rec[2][2][9][32];   // [dgsel][clip][tap][pix]
  const int t = threadIdx.x;
  const int g = blockIdx.x & 7;          // (b, half) -> XCD-resident KV slab
  const int pos = blockIdx.x >> 3;       // 0..215
  const int b = g >> 1;
  const int half = g & 1;
  const int pk = pos / 36;
  const int tile = pos % 36;
  const int n_base = half * 1152 + tile * 32;

  // ---- in-block record computation: 1152 records, ~4.5 per thread
#pragma unroll
  for (int i = 0; i < 5; ++i) {
    int rid = t + i * 256;
    if (rid < 1152) {
      int rpix = rid & 31;
      int rest = rid >> 5;               // 0..35 = (dgsel, clip, tap)
      int rtap = rest % 9;
      int rq = rest / 9;                 // 0..3
      int rclip = rq & 1;
      int dgsel = rq >> 1;
      int rn = n_base + rpix;
      int rh = rn / WID, rw = rn % WID;
      int dg = pk + dgsel * 6;
      const float* ob = offs + ((size_t)(b * 2 + rclip) * 216 + (size_t)(dg * 9 + rtap) * 2) * HW + rn;
      float oy = ob[0];
      float ox = ob[HW];
      float py = (float)(rh - 1 + rtap / 3) + oy;
      float px = (float)(rw - 1 + rtap % 3) + ox;
      float y0f = floorf(py), x0f = floorf(px);
      int y0 = (int)y0f, x0 = (int)x0f;
      float wy1 = py - y0f, wx1 = px - x0f;
      float wy0 = 1.f - wy1, wx0 = 1.f - wx1;
      unsigned ip[2];
      float wv[4];
#pragma unroll
      for (int cy = 0; cy < 2; ++cy) {
        int yi = y0 + cy;
        float wyv = cy ? wy1 : wy0;
        int yc = yi < 0 ? 0 : (yi > 47 ? 47 : yi);
        bool vy = (unsigned)yi < 48u;
#pragma unroll
        for (int cx = 0; cx < 2; ++cx) {
          int xi = x0 + cx;
          float wxv = cx ? wx1 : wx0;
          int xc = xi < 0 ? 0 : (xi > 47 ? 47 : xi);
          bool vx = (unsigned)xi < 48u;
          float wgt = (vy && vx) ? wyv * wxv : 0.f;
          int ci = cy * 2 + cx;
          wv[ci] = wgt;
          ((unsigned short*)ip)[ci] = (unsigned short)(yc * WID + xc);
        }
      }
      uint4 rc;
      rc.x = ip[0];
      rc.y = ip[1];
      rc.z = __builtin_bit_cast(unsigned, pk_h2(wv[0], wv[1]));
      rc.w = __builtin_bit_cast(unsigned, pk_h2(wv[2], wv[3]));
      rec[dgsel][rclip][rtap][rpix] = rc;
    }
  }

  const int l8 = t & 7;
  const int csel = l8 >> 2;      // corner slot: 0 -> A/C, 1 -> B/D
  const int chq = l8 & 3;        // 8-channel quarter within the 32-ch head-pair
  const int pix = t >> 3;
  const int n = n_base + pix;

  // q: 8 channels for this lane's quarter
  half2v qh[4];
  {
    const float* qb = qp + ((size_t)b * HW + n) * 192 + pk * 32 + chq * 8;
    float4 v0 = *(const float4*)qb;
    float4 v1 = *(const float4*)(qb + 4);
    qh[0] = pk_h2(v0.x * 0.25f, v0.y * 0.25f);
    qh[1] = pk_h2(v0.z * 0.25f, v0.w * 0.25f);
    qh[2] = pk_h2(v1.x * 0.25f, v1.y * 0.25f);
    qh[3] = pk_h2(v1.z * 0.25f, v1.w * 0.25f);
  }

  __syncthreads();

  float sc[18];

  // ---- K phase: dense [HW][32] plane for (bc, k, pk); pure load+fdot body
#pragma unroll
  for (int c = 0; c < 2; ++c) {
    const unsigned short* kb = kvp + (((size_t)(b * 2 + c) * 2 + 0) * 6 + pk) * HW * 32 + chq * 8;
#pragma unroll
    for (int kk = 0; kk < 9; ++kk) {
      uint4 rc = rec[0][c][kk][pix];
      float s = 0.f;
#pragma unroll
      for (int r = 0; r < 2; ++r) {
        unsigned pr = r ? rc.y : rc.x;
        unsigned idx = csel ? (pr >> 16) : (pr & 0xFFFFu);
        half2v wp = __builtin_bit_cast(half2v, r ? rc.w : rc.z);
        _Float16 wh = csel ? wp.y : wp.x;
        uint4 u = *(const uint4*)(kb + (size_t)idx * 32);
        float d = __builtin_amdgcn_fdot2(qh[0], __builtin_bit_cast(half2v, u.x), 0.f, false);
        d = __builtin_amdgcn_fdot2(qh[1], __builtin_bit_cast(half2v, u.y), d, false);
        d = __builtin_amdgcn_fdot2(qh[2], __builtin_bit_cast(half2v, u.z), d, false);
        d = __builtin_amdgcn_fdot2(qh[3], __builtin_bit_cast(half2v, u.w), d, false);
        s += (float)wh * d;
      }
      sc[c * 9 + kk] = s;
    }
  }

  // ---- batched cross-lane reduction
#pragma unroll
  for (int j = 0; j < 18; ++j) sc[j] += __shfl_xor(sc[j], 1, 64);
#pragma unroll
  for (int j = 0; j < 18; ++j) sc[j] += __shfl_xor(sc[j], 4, 64);

  // ---- softmax over 18 taps (in registers, redundant per lane)
  {
    float m = -1e30f;
#pragma unroll
    for (int j = 0; j < 18; ++j) m = fmaxf(m, sc[j]);
    float sum = 0.f;
#pragma unroll
    for (int j = 0; j < 18; ++j) { float ev = __expf(sc[j] - m); sc[j] = ev; sum += ev; }
    float inv = 1.f / sum;
#pragma unroll
    for (int j = 0; j < 18; ++j) sc[j] *= inv;
  }

  // ---- V phase: dense [HW][32] plane for (bc, v, pk)
  float acc[8];
#pragma unroll
  for (int i = 0; i < 8; ++i) acc[i] = 0.f;
#pragma unroll
  for (int c = 0; c < 2; ++c) {
    const unsigned short* vb = kvp + (((size_t)(b * 2 + c) * 2 + 1) * 6 + pk) * HW * 32 + chq * 8;
#pragma unroll
    for (int kk = 0; kk < 9; ++kk) {
      uint4 rc = rec[1][c][kk][pix];
      float at = sc[c * 9 + kk];
#pragma unroll
      for (int r = 0; r < 2; ++r) {
        unsigned pr = r ? rc.y : rc.x;
        unsigned idx = csel ? (pr >> 16) : (pr & 0xFFFFu);
        half2v wp = __builtin_bit_cast(half2v, r ? rc.w : rc.z);
        _Float16 wh = csel ? wp.y : wp.x;
        uint4 u = *(const uint4*)(vb + (size_t)idx * 32);
        float cw = (float)wh * at;
        half2v v0 = __builtin_bit_cast(half2v, u.x);
        half2v v1 = __builtin_bit_cast(half2v, u.y);
        half2v v2 = __builtin_bit_cast(half2v, u.z);
        half2v v3 = __builtin_bit_cast(half2v, u.w);
        acc[0] += cw * (float)v0.x; acc[1] += cw * (float)v0.y;
        acc[2] += cw * (float)v1.x; acc[3] += cw * (float)v1.y;
        acc[4] += cw * (float)v2.x; acc[5] += cw * (float)v2.y;
        acc[6] += cw * (float)v3.x; acc[7] += cw * (float)v3.y;
      }
    }
  }

  // cross-corner-lane reduce (lane ^ 4 holds the other corner slot)
#pragma unroll
  for (int i = 0; i < 8; ++i) acc[i] += __shfl_xor(acc[i], 4, 64);

  if (csel == 0) {
    float* orow = o_ws + ((size_t)b * HW + n) * 192 + pk * 32 + chq * 8;
    float4 r0; r0.x = acc[0]; r0.y = acc[1]; r0.z = acc[2]; r0.w = acc[3];
    float4 r1; r1.x = acc[4]; r1.y = acc[5]; r1.z = acc[6]; r1.w = acc[7];
    *(float4*)orow = r0;
    *(float4*)(orow + 4) = r1;
  }
}

// ---------------- MLP via MFMA: one block per 16-pixel tile
__global__ __launch_bounds__(256) void mlp_mfma(
    const float* __restrict__ o_ws, const unsigned* __restrict__ wf,
    const float* __restrict__ b1, const float* __restrict__ b2,
    float* __restrict__ out)
{
  __shared__ unsigned ldsO[16 * 100];
  __shared__ unsigned ldsH[16 * 196];
  const unsigned* w1f = wf + 216 * 256;
  const unsigned* w2f = wf + 360 * 256;
  const int blk = blockIdx.x;
  const int b = blk / 144;
  const int n0 = (blk % 144) * 16;
  const int t = threadIdx.x;
  const int w = t >> 6, l = t & 63;

  for (int i = t; i < 16 * 96; i += 256) {
    int pix = i / 96, cp = i % 96;
    const float2 s = *(const float2*)(o_ws + ((size_t)(b * HW) + n0 + pix) * 192 + 2 * cp);
    ldsO[pix * 100 + cp] = pack_bf2(s.x, s.y);
  }
  __syncthreads();

  f32x4 acc1[6];
#pragma unroll
  for (int a = 0; a < 6; ++a) acc1[a] = (f32x4){0.f, 0.f, 0.f, 0.f};
#pragma unroll
  for (int ks = 0; ks < 6; ++ks) {
    bf16x8 af = *(const bf16x8*)&ldsO[(l & 15) * 100 + ks * 16 + (l >> 4) * 4];
#pragma unroll
    for (int nfi = 0; nfi < 6; ++nfi) {
      int nf = w * 6 + nfi;
      bf16x8 bfr = ((const bf16x8*)w1f)[(nf * 6 + ks) * 64 + l];
      acc1[nfi] = __builtin_amdgcn_mfma_f32_16x16x32_bf16(af, bfr, acc1[nfi], 0, 0, 0);
    }
  }

  {
    unsigned short* ldsHu = (unsigned short*)ldsH;
#pragma unroll
    for (int nfi = 0; nfi < 6; ++nfi) {
      int hc = (w * 6 + nfi) * 16 + (l & 15);
      float bs = b1[hc];
#pragma unroll
      for (int j = 0; j < 4; ++j) {
        int pix = (l >> 4) * 4 + j;
        float x = acc1[nfi][j] + bs;
        float gl = 0.5f * x * (1.f + erff(x * 0.70710678118654752f));
        ldsHu[pix * 392 + hc] = bf16_of(gl);
      }
    }
  }
  __syncthreads();

  f32x4 acc2[3];
#pragma unroll
  for (int a = 0; a < 3; ++a) acc2[a] = (f32x4){0.f, 0.f, 0.f, 0.f};
#pragma unroll
  for (int ks = 0; ks < 12; ++ks) {
    bf16x8 af = *(const bf16x8*)&ldsH[(l & 15) * 196 + ks * 16 + (l >> 4) * 4];
#pragma unroll
    for (int nfi = 0; nfi < 3; ++nfi) {
      int nf = w * 3 + nfi;
      bf16x8 bfr = ((const bf16x8*)w2f)[(nf * 12 + ks) * 64 + l];
      acc2[nfi] = __builtin_amdgcn_mfma_f32_16x16x32_bf16(af, bfr, acc2[nfi], 0, 0, 0);
    }
  }

#pragma unroll
  for (int nfi = 0; nfi < 3; ++nfi) {
    int oc = (w * 3 + nfi) * 16 + (l & 15);
    float bs = b2[oc];
#pragma unroll
    for (int j = 0; j < 4; ++j) {
      int pix = (l >> 4) * 4 + j;
      float res = o_ws[((size_t)(b * HW) + n0 + pix) * 192 + oc];
      out[((size_t)b * 192 + oc) * HW + n0 + pix] = acc2[nfi][j] + bs + res;
    }
  }
}

extern "C" void kernel_launch(void* const* d_in, const int* in_sizes, int n_in,
                              void* d_out, int out_size, void* d_ws, size_t ws_size,
                              hipStream_t stream) {
  const float* q = (const float*)d_in[0];
  const float* k = (const float*)d_in[1];
  const float* v = (const float*)d_in[2];
  const float* offset = (const float*)d_in[3];
  const float* wq = (const float*)d_in[4];
  const float* bq = (const float*)d_in[5];
  const float* wk = (const float*)d_in[6];
  const float* bk = (const float*)d_in[7];
  const float* wv = (const float*)d_in[8];
  const float* bv = (const float*)d_in[9];
  const float* w1 = (const float*)d_in[10];
  const float* b1 = (const float*)d_in[11];
  const float* w2 = (const float*)d_in[12];
  const float* b2 = (const float*)d_in[13];
  float* out = (float*)d_out;

  float* qp_t = (float*)d_ws;                                    // 4*2304*192 f32
  float* o_ws = qp_t + (size_t)4 * HW * 192;                     // 4*2304*192 f32
  unsigned short* kvp = (unsigned short*)(o_ws + (size_t)4 * HW * 192);  // 8*2*6*2304*32 u16
  unsigned* wfb = (unsigned*)(kvp + (size_t)8 * 2 * 6 * HW * 32);        // 504*256 u32

  prep_w<<<dim3(126), dim3(256), 0, stream>>>(wq, wk, wv, w1, w2, wfb);
  proj_mfma<<<dim3(36, 20), dim3(256), 0, stream>>>(q, k, v, wfb, bq, bk, bv, qp_t, kvp);
  attn_kernel<<<dim3(1728), dim3(256), 0, stream>>>(qp_t, kvp, offset, o_ws);
  mlp_mfma<<<dim3(576), dim3(256), 0, stream>>>(o_ws, wfb, b1, b2, out);
}